// Round 1
// baseline (445.792 us; speedup 1.0000x reference)
//
#include <hip/hip_runtime.h>
#include <math.h>

#define B_  8
#define T_  2048
#define S_  2048
#define D_  512

typedef _Float16 half8   __attribute__((ext_vector_type(8)));
typedef _Float16 half4_t __attribute__((ext_vector_type(4)));
typedef float    floatx4 __attribute__((ext_vector_type(4)));

__device__ __forceinline__ floatx4 mfma16(half8 a, half8 b, floatx4 c) {
  return __builtin_amdgcn_mfma_f32_16x16x32_f16(a, b, c, 0, 0, 0);
}

// ---------------------------------------------------------------------------
// Kernel 1: Vt[b][d][s] = (fp16) attn[b][s][d]
// ---------------------------------------------------------------------------
__global__ __launch_bounds__(256) void transpose_cast_kernel(
    const float* __restrict__ attn, _Float16* __restrict__ Vt) {
  __shared__ _Float16 tile[32][33];
  const int tx = threadIdx.x, ty = threadIdx.y;
  const int b = blockIdx.z, s0 = blockIdx.y * 32, d0 = blockIdx.x * 32;
  const float* src = attn + ((size_t)b * S_ + s0) * D_ + d0;
#pragma unroll
  for (int i = 0; i < 4; ++i) {
    int s = ty + i * 8;
    tile[tx][s] = (_Float16)src[(size_t)s * D_ + tx];
  }
  __syncthreads();
  _Float16* dst = Vt + ((size_t)b * D_ + d0) * S_ + s0;
#pragma unroll
  for (int i = 0; i < 4; ++i) {
    int d = ty + i * 8;
    dst[(size_t)d * S_ + tx] = tile[d][tx];
  }
}

// ---------------------------------------------------------------------------
// Kernel 2: K16[i][e] = (fp16)( sum_d attn[i][d] * W[e][d] + bias[e] )
//   block tile 128x128, 4 waves each 64x64, K-chunks of 64, fp16 MFMA.
// ---------------------------------------------------------------------------
__global__ __launch_bounds__(256, 2) void keys_gemm_kernel(
    const float* __restrict__ X, const float* __restrict__ W,
    const float* __restrict__ bias, _Float16* __restrict__ K16) {
  __shared__ alignas(16) _Float16 Xs[128][72];
  __shared__ alignas(16) _Float16 Ws[128][72];
  const int t = threadIdx.x;
  const int wave = t >> 6, lane = t & 63, q = lane >> 4, n = lane & 15;
  const int wm = wave >> 1, wn = wave & 1;
  const int m0 = blockIdx.x * 128, n0 = blockIdx.y * 128;

  floatx4 acc[4][4];
#pragma unroll
  for (int i = 0; i < 4; ++i)
#pragma unroll
    for (int j = 0; j < 4; ++j) {
      floatx4 z = {0.f, 0.f, 0.f, 0.f};
      acc[i][j] = z;
    }

  for (int kc = 0; kc < 8; ++kc) {
    const int k0 = kc * 64;
#pragma unroll
    for (int i = 0; i < 8; ++i) {
      int seg = i * 256 + t;           // 2048 segs: 128 rows x 16 float4
      int row = seg >> 4, c4 = (seg & 15) * 4;
      floatx4 xv = *(const floatx4*)&X[(size_t)(m0 + row) * D_ + k0 + c4];
      floatx4 wv = *(const floatx4*)&W[(size_t)(n0 + row) * D_ + k0 + c4];
      half4_t xh, wh;
#pragma unroll
      for (int j = 0; j < 4; ++j) { xh[j] = (_Float16)xv[j]; wh[j] = (_Float16)wv[j]; }
      *(half4_t*)&Xs[row][c4] = xh;
      *(half4_t*)&Ws[row][c4] = wh;
    }
    __syncthreads();
#pragma unroll
    for (int kk = 0; kk < 2; ++kk) {
      half8 a[4], bb[4];
#pragma unroll
      for (int mt = 0; mt < 4; ++mt)
        a[mt] = *(const half8*)&Xs[wm * 64 + mt * 16 + n][kk * 32 + q * 8];
#pragma unroll
      for (int nt = 0; nt < 4; ++nt)
        bb[nt] = *(const half8*)&Ws[wn * 64 + nt * 16 + n][kk * 32 + q * 8];
#pragma unroll
      for (int mt = 0; mt < 4; ++mt)
#pragma unroll
        for (int nt = 0; nt < 4; ++nt)
          acc[mt][nt] = mfma16(a[mt], bb[nt], acc[mt][nt]);
    }
    __syncthreads();
  }

#pragma unroll
  for (int nt = 0; nt < 4; ++nt) {
    int col = n0 + wn * 64 + nt * 16 + n;
    float bv = bias[col];
#pragma unroll
    for (int mt = 0; mt < 4; ++mt)
#pragma unroll
      for (int r = 0; r < 4; ++r) {
        int row = m0 + wm * 64 + mt * 16 + q * 4 + r;
        K16[(size_t)row * D_ + col] = (_Float16)(acc[mt][nt][r] + bv);
      }
  }
}

// ---------------------------------------------------------------------------
// Kernel 3: flash attention.
//   BM=32 rows/block, s-tiles of 128 (each wave owns 32 score cols),
//   Q resident in LDS (fp16), K/V fragments loaded directly from global,
//   P through LDS (C-layout -> A-layout), O 32x128/wave in registers.
// ---------------------------------------------------------------------------
__global__ __launch_bounds__(256, 2) void flash_kernel(
    const float* __restrict__ Qf, const _Float16* __restrict__ K16,
    const _Float16* __restrict__ Vt, float* __restrict__ out) {
  __shared__ alignas(16) _Float16 Qs[32][520];
  __shared__ alignas(16) _Float16 Ps[32][136];
  __shared__ alignas(16) float redmax[32][4];
  __shared__ alignas(16) float redsum[32][4];

  const int t = threadIdx.x;
  const int wave = t >> 6, lane = t & 63, q = lane >> 4, n = lane & 15;
  const int bid = blockIdx.x;
  const int b = bid & 7;            // batch = bid%8 -> one batch per XCD (L2 locality)
  const int t0 = (bid >> 3) * 32;

  // ---- stage Q (fp32 -> fp16) into LDS, resident for whole kernel ----
  const float* Qbase = Qf + ((size_t)b * T_ + t0) * D_;
#pragma unroll
  for (int i = 0; i < 16; ++i) {
    int seg = i * 256 + t;               // 4096 segs: 32 rows x 128 float4
    int row = seg >> 7, c4 = (seg & 127) * 4;
    floatx4 v = *(const floatx4*)&Qbase[(size_t)row * D_ + c4];
    half4_t h;
#pragma unroll
    for (int j = 0; j < 4; ++j) h[j] = (_Float16)v[j];
    *(half4_t*)&Qs[row][c4] = h;
  }

  floatx4 O[8][2];
#pragma unroll
  for (int ng = 0; ng < 8; ++ng)
#pragma unroll
    for (int mt = 0; mt < 2; ++mt) {
      floatx4 z = {0.f, 0.f, 0.f, 0.f};
      O[ng][mt] = z;
    }
  float mst[2][4], lst[2][4];
#pragma unroll
  for (int mt = 0; mt < 2; ++mt)
#pragma unroll
    for (int r = 0; r < 4; ++r) { mst[mt][r] = -INFINITY; lst[mt][r] = 0.f; }

  __syncthreads();

  const _Float16* Kb = K16 + (size_t)b * S_ * D_;
  const _Float16* Vb = Vt + (size_t)b * D_ * S_;

  for (int st = 0; st < S_ / 128; ++st) {
    const int s0 = st * 128;

    // ---------------- QK^T: wave computes 32 rows x 32 cols -------------
    floatx4 Sc[2][2];
#pragma unroll
    for (int mt = 0; mt < 2; ++mt)
#pragma unroll
      for (int nt = 0; nt < 2; ++nt) {
        floatx4 z = {0.f, 0.f, 0.f, 0.f};
        Sc[mt][nt] = z;
      }
    const _Float16* kp0 = Kb + (size_t)(s0 + wave * 32 + n) * D_ + q * 8;
    const _Float16* kp1 = kp0 + (size_t)16 * D_;
#pragma unroll 4
    for (int kk = 0; kk < 16; ++kk) {
      half8 a0 = *(const half8*)&Qs[n][kk * 32 + q * 8];
      half8 a1 = *(const half8*)&Qs[16 + n][kk * 32 + q * 8];
      half8 b0 = *(const half8*)(kp0 + kk * 32);
      half8 b1 = *(const half8*)(kp1 + kk * 32);
      Sc[0][0] = mfma16(a0, b0, Sc[0][0]);
      Sc[1][0] = mfma16(a1, b0, Sc[1][0]);
      Sc[0][1] = mfma16(a0, b1, Sc[0][1]);
      Sc[1][1] = mfma16(a1, b1, Sc[1][1]);
    }

    // ---------------- online softmax ------------------------------------
    // per-row max over this wave's 32 cols
#pragma unroll
    for (int mt = 0; mt < 2; ++mt)
#pragma unroll
      for (int r = 0; r < 4; ++r) {
        float v = fmaxf(Sc[mt][0][r], Sc[mt][1][r]);
        v = fmaxf(v, __shfl_xor(v, 1, 16));
        v = fmaxf(v, __shfl_xor(v, 2, 16));
        v = fmaxf(v, __shfl_xor(v, 4, 16));
        v = fmaxf(v, __shfl_xor(v, 8, 16));
        if (n == 0) redmax[mt * 16 + q * 4 + r][wave] = v;
      }
    __syncthreads();

    float alpha[2][4];
#pragma unroll
    for (int mt = 0; mt < 2; ++mt)
#pragma unroll
      for (int r = 0; r < 4; ++r) {
        int row = mt * 16 + q * 4 + r;
        floatx4 rm = *(const floatx4*)&redmax[row][0];
        float tm = fmaxf(fmaxf(rm[0], rm[1]), fmaxf(rm[2], rm[3]));
        float mn = fmaxf(mst[mt][r], tm);
        alpha[mt][r] = __expf(mst[mt][r] - mn);
        mst[mt][r] = mn;
      }

    // P = exp(S - m), row sums, write P to LDS (fp16)
#pragma unroll
    for (int mt = 0; mt < 2; ++mt)
#pragma unroll
      for (int r = 0; r < 4; ++r) {
        float p0 = __expf(Sc[mt][0][r] - mst[mt][r]);
        float p1 = __expf(Sc[mt][1][r] - mst[mt][r]);
        int row = mt * 16 + q * 4 + r;
        Ps[row][wave * 32 + n] = (_Float16)p0;
        Ps[row][wave * 32 + 16 + n] = (_Float16)p1;
        float s = p0 + p1;
        s += __shfl_xor(s, 1, 16);
        s += __shfl_xor(s, 2, 16);
        s += __shfl_xor(s, 4, 16);
        s += __shfl_xor(s, 8, 16);
        if (n == 0) redsum[row][wave] = s;
      }

    // rescale O by alpha
#pragma unroll
    for (int ng = 0; ng < 8; ++ng)
#pragma unroll
      for (int mt = 0; mt < 2; ++mt)
#pragma unroll
        for (int r = 0; r < 4; ++r) O[ng][mt][r] *= alpha[mt][r];
    __syncthreads();

    // l update
#pragma unroll
    for (int mt = 0; mt < 2; ++mt)
#pragma unroll
      for (int r = 0; r < 4; ++r) {
        int row = mt * 16 + q * 4 + r;
        floatx4 rs = *(const floatx4*)&redsum[row][0];
        lst[mt][r] = lst[mt][r] * alpha[mt][r] + (rs[0] + rs[1] + rs[2] + rs[3]);
      }

    // ---------------- PV: O[:, wave*128 .. +128) += P @ V ---------------
    const _Float16* vp = Vb + (size_t)(wave * 128 + n) * S_ + s0 + q * 8;
#pragma unroll
    for (int kk = 0; kk < 4; ++kk) {
      half8 a0 = *(const half8*)&Ps[n][kk * 32 + q * 8];
      half8 a1 = *(const half8*)&Ps[16 + n][kk * 32 + q * 8];
#pragma unroll
      for (int ng = 0; ng < 8; ++ng) {
        half8 bv = *(const half8*)(vp + (size_t)ng * 16 * S_ + kk * 32);
        O[ng][0] = mfma16(a0, bv, O[ng][0]);
        O[ng][1] = mfma16(a1, bv, O[ng][1]);
      }
    }
    __syncthreads();   // protects Ps/redmax/redsum for next s-tile
  }

  // ---- epilogue: out = O / l ----
  float* ob = out + ((size_t)b * T_ + t0) * D_;
#pragma unroll
  for (int ng = 0; ng < 8; ++ng)
#pragma unroll
    for (int mt = 0; mt < 2; ++mt)
#pragma unroll
      for (int r = 0; r < 4; ++r) {
        int row = mt * 16 + q * 4 + r;
        int col = wave * 128 + ng * 16 + n;
        ob[(size_t)row * D_ + col] = O[ng][mt][r] / lst[mt][r];
      }
}

// ---------------------------------------------------------------------------
extern "C" void kernel_launch(void* const* d_in, const int* in_sizes, int n_in,
                              void* d_out, int out_size, void* d_ws, size_t ws_size,
                              hipStream_t stream) {
  (void)in_sizes; (void)n_in; (void)out_size; (void)ws_size;
  const float* main_in = (const float*)d_in[0];   // [B,T,D]
  const float* attn_in = (const float*)d_in[1];   // [B,S,D]
  const float* W_f     = (const float*)d_in[2];   // [D,D]
  const float* b_f     = (const float*)d_in[3];   // [D]
  float* out = (float*)d_out;                     // [B,T,D] fp32

  _Float16* K16 = (_Float16*)d_ws;                       // [B*S, D] fp16
  _Float16* Vt  = K16 + (size_t)B_ * S_ * D_;            // [B, D, S] fp16

  transpose_cast_kernel<<<dim3(D_ / 32, S_ / 32, B_), dim3(32, 8, 1), 0, stream>>>(
      attn_in, Vt);
  keys_gemm_kernel<<<dim3((B_ * S_) / 128, D_ / 128), 256, 0, stream>>>(
      attn_in, W_f, b_f, K16);
  flash_kernel<<<(B_ * T_) / 32, 256, 0, stream>>>(main_in, K16, Vt, out);
}